// Round 5
// baseline (84.342 us; speedup 1.0000x reference)
//
#include <hip/hip_runtime.h>
#include <math.h>

// ---------------------------------------------------------------------------
// Strip-scan with replication, no global atomics anywhere.
// Block b = s*R + r owns row-strip s (rows x G cells in LDS) and scans rect
// subset r (contiguous, coalesced). Patch span is <= 4 cells per axis
// (dims <= 3/G), so the update is a fully-unrolled predicated 4x4 patch of
// LDS atomics with ox[4]/oy[4] precomputed once per rect. Full strip is
// written out (zeros included) -> ws needs no zero-init.
// ---------------------------------------------------------------------------
__global__ __launch_bounds__(1024, 2)
void strip_scan(const float* __restrict__ boundary,
                const float2* __restrict__ xy,
                const float2* __restrict__ dims,
                const float* __restrict__ w,
                float* __restrict__ ws,
                int G, int R, int rows, int n_rects)
{
    extern __shared__ float acc[];           // rows * G floats
    const int b   = blockIdx.x;
    const int s   = b / R;                   // strip index
    const int r   = b % R;                   // rect-subset index
    const int tid = threadIdx.x;
    const int stripElems = rows * G;
    const int row0 = s * rows;
    const int row1 = row0 + rows - 1;

    for (int c = tid; c < stripElems; c += blockDim.x) acc[c] = 0.0f;
    __syncthreads();

    const float xmin = boundary[0], ymin = boundary[1];
    const float xmax = boundary[2], ymax = boundary[3];
    const float lx = (xmax - xmin) / (float)G;
    const float ly = (ymax - ymin) / (float)G;
    const float inv_lx = (float)G / (xmax - xmin);
    const float inv_ly = (float)G / (ymax - ymin);
    const float inv_area = inv_lx * inv_ly;

    const int chunk = (n_rects + R - 1) / R;
    const int lo = r * chunk;
    const int hi = min(lo + chunk, n_rects);

    for (int n = lo + tid; n < hi; n += blockDim.x) {
        float2 p = xy[n];
        float2 d = dims[n];
        const float bx0 = p.x, bx1 = p.x + d.x;

        int ri0 = (int)floorf((bx0 - xmin) * inv_lx);
        int ri1 = (int)floorf((bx1 - xmin) * inv_lx);
        int i0 = max(max(ri0, 0), row0);
        int i1 = min(min(ri1, G - 1), row1);
        if (i0 > i1) continue;                        // misses this strip

        const float by0 = p.y, by1 = p.y + d.y;
        int j0 = max((int)floorf((by0 - ymin) * inv_ly), 0);
        int j1 = min((int)floorf((by1 - ymin) * inv_ly), G - 1);
        if (j0 > j1) continue;

        const float cw = w[n] * inv_area;

        if (i1 - i0 <= 3 && j1 - j0 <= 3) {
            // Hot path: straight-line predicated 4x4 patch.
            float oxv[4], oyv[4];
            #pragma unroll
            for (int di = 0; di < 4; ++di) {
                int   i   = i0 + di;
                float gx0 = xmin + (float)i * lx;
                float ox  = fminf(gx0 + lx, bx1) - fmaxf(gx0, bx0);
                oxv[di] = (i <= i1) ? fmaxf(ox, 0.0f) : 0.0f;
            }
            #pragma unroll
            for (int dj = 0; dj < 4; ++dj) {
                int   j   = j0 + dj;
                float gy0 = ymin + (float)j * ly;
                float oy  = fminf(gy0 + ly, by1) - fmaxf(gy0, by0);
                oyv[dj] = (j <= j1) ? fmaxf(oy, 0.0f) : 0.0f;
            }
            #pragma unroll
            for (int di = 0; di < 4; ++di) {
                if (oxv[di] > 0.0f) {
                    float  cox  = cw * oxv[di];
                    float* rowp = acc + (i0 + di - row0) * G + j0;
                    #pragma unroll
                    for (int dj = 0; dj < 4; ++dj) {
                        if (oyv[dj] > 0.0f)
                            atomicAdd(rowp + dj, cox * oyv[dj]);
                    }
                }
            }
        } else {
            // Rare safety path (span > 4 can't happen with dims <= 3/G).
            for (int i = i0; i <= i1; ++i) {
                float gx0 = xmin + (float)i * lx;
                float ox  = fmaxf(fminf(gx0 + lx, bx1) - fmaxf(gx0, bx0), 0.0f);
                if (ox <= 0.0f) continue;
                float cox = cw * ox;
                float* rowp = acc + (i - row0) * G;
                for (int j = j0; j <= j1; ++j) {
                    float gy0 = ymin + (float)j * ly;
                    float oy  = fminf(gy0 + ly, by1) - fmaxf(gy0, by0);
                    if (oy > 0.0f) atomicAdd(rowp + j, cox * oy);
                }
            }
        }
    }
    __syncthreads();

    // Coalesced full-strip writeout (zeros included -> no ws memset needed).
    float* dst = ws + (size_t)b * stripElems;
    for (int c = tid; c < stripElems; c += blockDim.x) dst[c] = acc[c];
}

// ---------------------------------------------------------------------------
// Sum the R replicas of each strip into the output. Coalesced, no atomics.
// ---------------------------------------------------------------------------
__global__ __launch_bounds__(256)
void reduce_strips(const float* __restrict__ ws,
                   float* __restrict__ out,
                   int G, int R, int rows)
{
    const int c = blockIdx.x * blockDim.x + threadIdx.x;
    if (c >= G * G) return;
    const int i = c / G;
    const int j = c - i * G;
    const int s = i / rows;
    const int stripElems = rows * G;
    const int local = (i - s * rows) * G + j;

    const float* base = ws + (size_t)s * R * stripElems + local;
    float sum = 0.0f;
    #pragma unroll 8
    for (int r = 0; r < R; ++r)
        sum += base[(size_t)r * stripElems];
    out[c] = sum;
}

// ---------------------------------------------------------------------------
// Fallback for odd shapes / tiny workspace: direct global-atomic scatter.
// ---------------------------------------------------------------------------
__global__ void scatter_direct(const float* __restrict__ boundary,
                               const float2* __restrict__ xy,
                               const float2* __restrict__ dims,
                               const float* __restrict__ w,
                               float* __restrict__ out,
                               int G, int n_rects)
{
    int n = blockIdx.x * blockDim.x + threadIdx.x;
    if (n >= n_rects) return;
    float xmin = boundary[0], ymin = boundary[1];
    float xmax = boundary[2], ymax = boundary[3];
    float lx = (xmax - xmin) / (float)G;
    float ly = (ymax - ymin) / (float)G;
    float2 p = xy[n]; float2 d = dims[n];
    float bx0 = p.x, by0 = p.y, bx1 = bx0 + d.x, by1 = by0 + d.y;
    float cw = w[n] / (lx * ly);
    int i0 = max((int)floorf((bx0 - xmin) / lx), 0);
    int i1 = min((int)floorf((bx1 - xmin) / lx), G - 1);
    int j0 = max((int)floorf((by0 - ymin) / ly), 0);
    int j1 = min((int)floorf((by1 - ymin) / ly), G - 1);
    for (int i = i0; i <= i1; ++i) {
        float gx0 = xmin + (float)i * lx;
        float ox = fmaxf(fminf(gx0 + lx, bx1) - fmaxf(gx0, bx0), 0.0f);
        if (ox <= 0.0f) continue;
        float cox = cw * ox;
        for (int j = j0; j <= j1; ++j) {
            float gy0 = ymin + (float)j * ly;
            float oy = fmaxf(fminf(gy0 + ly, by1) - fmaxf(gy0, by0), 0.0f);
            if (oy > 0.0f) atomicAdd(out + (size_t)i * G + j, cox * oy);
        }
    }
}

extern "C" void kernel_launch(void* const* d_in, const int* in_sizes, int n_in,
                              void* d_out, int out_size, void* d_ws, size_t ws_size,
                              hipStream_t stream) {
    const float*  boundary = (const float*)d_in[0];
    const float2* xy       = (const float2*)d_in[1];
    const float2* dims     = (const float2*)d_in[2];
    const float*  cweight  = (const float*)d_in[3];
    float* out = (float*)d_out;
    const int n_rects = in_sizes[1] / 2;

    int G = (int)lround(sqrt((double)out_size));
    const bool square = ((long long)G * G == (long long)out_size) && G > 0;

    // Smallest power-of-2 strip count S (dividing G) with strip <= 32 KB so
    // two 1024-thread blocks co-reside per CU; fall back to <= 64 KB.
    int S = 0, rows = 0;
    if (square) {
        for (int cand = 1; cand <= 256; cand <<= 1) {
            if (G % cand) continue;
            long long bytes = (long long)(G / cand) * G * 4;
            if (bytes <= 32 * 1024) { S = cand; rows = G / cand; break; }
        }
        if (S == 0) {
            for (int cand = 1; cand <= 256; cand <<= 1) {
                if (G % cand) continue;
                long long bytes = (long long)(G / cand) * G * 4;
                if (bytes <= 64 * 1024) { S = cand; rows = G / cand; break; }
            }
        }
    }
    int R = 0;
    if (S > 0) {
        R = 512 / S;                         // target 512 blocks = 2/CU
        if (R < 1) R = 1;
        long long need = (long long)S * R * rows * G * 4;
        while (R > 1 && need > (long long)ws_size) {
            R >>= 1;
            need = (long long)S * R * rows * G * 4;
        }
        if (need > (long long)ws_size) R = 0;
    }

    if (R > 0) {
        float* ws = (float*)d_ws;
        const int stripBytes = rows * G * 4;
        strip_scan<<<S * R, 1024, stripBytes, stream>>>(
            boundary, xy, dims, cweight, ws, G, R, rows, n_rects);
        reduce_strips<<<(G * G + 255) / 256, 256, 0, stream>>>(
            ws, out, G, R, rows);
    } else {
        hipMemsetAsync(out, 0, (size_t)out_size * sizeof(float), stream);
        const int block = 256;
        scatter_direct<<<(n_rects + block - 1) / block, block, 0, stream>>>(
            boundary, xy, dims, cweight, out, G, n_rects);
    }
}

// Round 6
// 82.326 us; speedup vs baseline: 1.0245x; 1.0245x over previous
//
#include <hip/hip_runtime.h>
#include <math.h>

// ---------------------------------------------------------------------------
// Strip-scan with replication, no global atomics anywhere.
// Block b = s*R + r owns row-strip s (rows x G cells in LDS) and scans rect
// subset r (contiguous, coalesced reads). Patch span <= 4 cells per axis
// (dims <= 3/G), so the update is a fully-unrolled predicated 4x4 patch of
// LDS atomics with ox[4]/oy[4] precomputed once per rect. Full strip is
// written out with float4 stores (zeros included) -> ws needs no zero-init.
// Traffic: scan S*4MB + ws R*256KB write; S=4,R=64 minimizes the sum.
// ---------------------------------------------------------------------------
__global__ __launch_bounds__(1024)
void strip_scan(const float* __restrict__ boundary,
                const float2* __restrict__ xy,
                const float2* __restrict__ dims,
                const float* __restrict__ w,
                float* __restrict__ ws,
                int G, int R, int rows, int n_rects)
{
    extern __shared__ float acc[];           // rows * G floats
    const int b   = blockIdx.x;
    const int s   = b / R;                   // strip index
    const int r   = b % R;                   // rect-subset index
    const int tid = threadIdx.x;
    const int stripElems = rows * G;
    const int row0 = s * rows;
    const int row1 = row0 + rows - 1;

    for (int c = tid; c < stripElems; c += blockDim.x) acc[c] = 0.0f;
    __syncthreads();

    const float xmin = boundary[0], ymin = boundary[1];
    const float xmax = boundary[2], ymax = boundary[3];
    const float lx = (xmax - xmin) / (float)G;
    const float ly = (ymax - ymin) / (float)G;
    const float inv_lx = (float)G / (xmax - xmin);
    const float inv_ly = (float)G / (ymax - ymin);
    const float inv_area = inv_lx * inv_ly;

    const int chunk = (n_rects + R - 1) / R;
    const int lo = r * chunk;
    const int hi = min(lo + chunk, n_rects);

    for (int n = lo + tid; n < hi; n += blockDim.x) {
        float2 p = xy[n];
        float2 d = dims[n];
        const float bx0 = p.x, bx1 = p.x + d.x;

        int ri0 = (int)floorf((bx0 - xmin) * inv_lx);
        int ri1 = (int)floorf((bx1 - xmin) * inv_lx);
        int i0 = max(max(ri0, 0), row0);
        int i1 = min(min(ri1, G - 1), row1);
        if (i0 > i1) continue;                        // misses this strip

        const float by0 = p.y, by1 = p.y + d.y;
        int j0 = max((int)floorf((by0 - ymin) * inv_ly), 0);
        int j1 = min((int)floorf((by1 - ymin) * inv_ly), G - 1);
        if (j0 > j1) continue;

        const float cw = w[n] * inv_area;

        if (i1 - i0 <= 3 && j1 - j0 <= 3) {
            // Hot path: straight-line predicated 4x4 patch.
            float oxv[4], oyv[4];
            #pragma unroll
            for (int di = 0; di < 4; ++di) {
                int   i   = i0 + di;
                float gx0 = xmin + (float)i * lx;
                float ox  = fminf(gx0 + lx, bx1) - fmaxf(gx0, bx0);
                oxv[di] = (i <= i1) ? fmaxf(ox, 0.0f) : 0.0f;
            }
            #pragma unroll
            for (int dj = 0; dj < 4; ++dj) {
                int   j   = j0 + dj;
                float gy0 = ymin + (float)j * ly;
                float oy  = fminf(gy0 + ly, by1) - fmaxf(gy0, by0);
                oyv[dj] = (j <= j1) ? fmaxf(oy, 0.0f) : 0.0f;
            }
            #pragma unroll
            for (int di = 0; di < 4; ++di) {
                if (oxv[di] > 0.0f) {
                    float  cox  = cw * oxv[di];
                    float* rowp = acc + (i0 + di - row0) * G + j0;
                    #pragma unroll
                    for (int dj = 0; dj < 4; ++dj) {
                        if (oyv[dj] > 0.0f)
                            atomicAdd(rowp + dj, cox * oyv[dj]);
                    }
                }
            }
        } else {
            // Safety path (span > 4 can't happen with dims <= 3/G).
            for (int i = i0; i <= i1; ++i) {
                float gx0 = xmin + (float)i * lx;
                float ox  = fmaxf(fminf(gx0 + lx, bx1) - fmaxf(gx0, bx0), 0.0f);
                if (ox <= 0.0f) continue;
                float cox = cw * ox;
                float* rowp = acc + (i - row0) * G;
                for (int j = j0; j <= j1; ++j) {
                    float gy0 = ymin + (float)j * ly;
                    float oy  = fminf(gy0 + ly, by1) - fmaxf(gy0, by0);
                    if (oy > 0.0f) atomicAdd(rowp + j, cox * oy);
                }
            }
        }
    }
    __syncthreads();

    // Coalesced float4 strip writeout (zeros included -> no ws memset).
    float4* dst = (float4*)(ws + (size_t)b * stripElems);
    const float4* src = (const float4*)acc;
    const int nvec = stripElems >> 2;
    for (int c = tid; c < nvec; c += blockDim.x) dst[c] = src[c];
}

// ---------------------------------------------------------------------------
// Sum the R replicas of each strip into the output. One cell per thread,
// coalesced strided reads, spread across the whole chip. No atomics.
// ---------------------------------------------------------------------------
__global__ __launch_bounds__(256)
void reduce_strips(const float* __restrict__ ws,
                   float* __restrict__ out,
                   int G, int R, int rows)
{
    const int c = blockIdx.x * blockDim.x + threadIdx.x;
    if (c >= G * G) return;
    const int i = c / G;
    const int j = c - i * G;
    const int s = i / rows;
    const int stripElems = rows * G;
    const int local = (i - s * rows) * G + j;

    const float* base = ws + (size_t)s * R * stripElems + local;
    float sum = 0.0f;
    #pragma unroll 16
    for (int r = 0; r < R; ++r)
        sum += base[(size_t)r * stripElems];
    out[c] = sum;
}

// ---------------------------------------------------------------------------
// Fallback for odd shapes / tiny workspace: direct global-atomic scatter.
// ---------------------------------------------------------------------------
__global__ void scatter_direct(const float* __restrict__ boundary,
                               const float2* __restrict__ xy,
                               const float2* __restrict__ dims,
                               const float* __restrict__ w,
                               float* __restrict__ out,
                               int G, int n_rects)
{
    int n = blockIdx.x * blockDim.x + threadIdx.x;
    if (n >= n_rects) return;
    float xmin = boundary[0], ymin = boundary[1];
    float xmax = boundary[2], ymax = boundary[3];
    float lx = (xmax - xmin) / (float)G;
    float ly = (ymax - ymin) / (float)G;
    float2 p = xy[n]; float2 d = dims[n];
    float bx0 = p.x, by0 = p.y, bx1 = bx0 + d.x, by1 = by0 + d.y;
    float cw = w[n] / (lx * ly);
    int i0 = max((int)floorf((bx0 - xmin) / lx), 0);
    int i1 = min((int)floorf((bx1 - xmin) / lx), G - 1);
    int j0 = max((int)floorf((by0 - ymin) / ly), 0);
    int j1 = min((int)floorf((by1 - ymin) / ly), G - 1);
    for (int i = i0; i <= i1; ++i) {
        float gx0 = xmin + (float)i * lx;
        float ox = fmaxf(fminf(gx0 + lx, bx1) - fmaxf(gx0, bx0), 0.0f);
        if (ox <= 0.0f) continue;
        float cox = cw * ox;
        for (int j = j0; j <= j1; ++j) {
            float gy0 = ymin + (float)j * ly;
            float oy = fmaxf(fminf(gy0 + ly, by1) - fmaxf(gy0, by0), 0.0f);
            if (oy > 0.0f) atomicAdd(out + (size_t)i * G + j, cox * oy);
        }
    }
}

extern "C" void kernel_launch(void* const* d_in, const int* in_sizes, int n_in,
                              void* d_out, int out_size, void* d_ws, size_t ws_size,
                              hipStream_t stream) {
    const float*  boundary = (const float*)d_in[0];
    const float2* xy       = (const float2*)d_in[1];
    const float2* dims     = (const float2*)d_in[2];
    const float*  cweight  = (const float*)d_in[3];
    float* out = (float*)d_out;
    const int n_rects = in_sizes[1] / 2;

    int G = (int)lround(sqrt((double)out_size));
    const bool square = ((long long)G * G == (long long)out_size) && G > 0;

    // Smallest power-of-2 strip count S (dividing G) with strip <= 64 KB:
    // minimizes scan replication (S * input re-reads) while fitting LDS.
    int S = 0, rows = 0;
    if (square) {
        for (int cand = 1; cand <= 256; cand <<= 1) {
            if (G % cand) continue;
            long long bytes = (long long)(G / cand) * G * 4;
            if (bytes <= 64 * 1024) { S = cand; rows = G / cand; break; }
        }
    }
    int R = 0;
    if (S > 0) {
        R = 256 / S;                         // S*R = 256 blocks = 1/CU
        if (R < 1) R = 1;
        long long need = (long long)S * R * rows * G * 4;
        while (R > 1 && need > (long long)ws_size) {
            R >>= 1;
            need = (long long)S * R * rows * G * 4;
        }
        if (need > (long long)ws_size) R = 0;
    }

    if (R > 0) {
        float* ws = (float*)d_ws;
        const int stripBytes = rows * G * 4;
        strip_scan<<<S * R, 1024, stripBytes, stream>>>(
            boundary, xy, dims, cweight, ws, G, R, rows, n_rects);
        reduce_strips<<<(G * G + 255) / 256, 256, 0, stream>>>(
            ws, out, G, R, rows);
    } else {
        hipMemsetAsync(out, 0, (size_t)out_size * sizeof(float), stream);
        const int block = 256;
        scatter_direct<<<(n_rects + block - 1) / block, block, 0, stream>>>(
            boundary, xy, dims, cweight, out, G, n_rects);
    }
}